// Round 6
// baseline (932.804 us; speedup 1.0000x reference)
//
#include <hip/hip_runtime.h>

#define N_NODES 50000
#define N_EDGES 1600000
#define R_WAV 4
#define D 128
#define NB 391                 // ceil(50000/128) buckets of 128 rows
#define CHUNK 4096             // edges per hist/partition block
#define NPBLK ((N_EDGES + CHUNK - 1) / CHUNK)   // 391
#define MAXB 4800              // bucket capacity (mean 4092, sigma ~64)
#define STCAP 5824             // MAXB + 128*8 padding headroom
#define BSLACK 1024            // fixed per-bucket padded slack in cv4

typedef unsigned int u32;
typedef unsigned short u16;

// fp32 -> bf16 bits, round-to-nearest-even
static __device__ inline u16 f2bf(float f) {
    u32 u = __float_as_uint(f);
    u = (u + 0x7FFFu + ((u >> 16) & 1u)) >> 16;
    return (u16)u;
}
static __device__ inline float bf_lo(u32 u) { return __uint_as_float(u << 16); }
static __device__ inline float bf_hi(u32 u) { return __uint_as_float(u & 0xFFFF0000u); }

// ------------- GEMM: h = x @ W, bf16 SLICED output [4][N][32] ----------------
__global__ __launch_bounds__(128) void gemm_xw(const float* __restrict__ x,
                                               const float* __restrict__ W,
                                               u16* __restrict__ h) {
    __shared__ float xs[4 * 128];
    const int j = threadIdx.x;
    const int row0 = blockIdx.x * 4;
    for (int t = j; t < 512; t += 128) xs[t] = x[(size_t)row0 * D + t];
    __syncthreads();
    float a0 = 0.f, a1 = 0.f, a2 = 0.f, a3 = 0.f;
#pragma unroll 8
    for (int k = 0; k < 128; ++k) {
        const float w = W[k * D + j];
        a0 += xs[k] * w;
        a1 += xs[128 + k] * w;
        a2 += xs[256 + k] * w;
        a3 += xs[384 + k] * w;
    }
    const size_t sb = ((size_t)(j >> 5) * N_NODES) * 32 + (j & 31);
    h[sb + (size_t)(row0 + 0) * 32] = f2bf(a0);
    h[sb + (size_t)(row0 + 1) * 32] = f2bf(a1);
    h[sb + (size_t)(row0 + 2) * 32] = f2bf(a2);
    h[sb + (size_t)(row0 + 3) * 32] = f2bf(a3);
}

// ------------- batched bucket histogram: grid (NPBLK, R_WAV) -----------------
__global__ __launch_bounds__(256) void bucket_hist_all(const int* __restrict__ rows_all,
                                                       int* __restrict__ cnt4) {
    __shared__ int lh[NB];
    const int r = blockIdx.y;
    const int* rows = rows_all + (size_t)r * N_EDGES;
    int* cnt = cnt4 + r * NB;
    const int tid = threadIdx.x;
    for (int i = tid; i < NB; i += 256) lh[i] = 0;
    __syncthreads();
    const int e0 = blockIdx.x * CHUNK;
    const int e1 = min(e0 + CHUNK, N_EDGES);
    for (int i = e0 + tid; i < e1; i += 256) atomicAdd(&lh[rows[i] >> 7], 1);
    __syncthreads();
    for (int i = tid; i < NB; i += 256) {
        const int c = lh[i];
        if (c) atomicAdd(&cnt[i], c);
    }
}

// ------------- batched scan of bucket counts: grid R_WAV ---------------------
__global__ __launch_bounds__(512) void scan_buckets_all(const int* __restrict__ cnt4,
                                                        int* __restrict__ bptr4,
                                                        int* __restrict__ bcur4) {
    __shared__ int sa[512], sb[512];
    const int r = blockIdx.x;
    const int* cnt = cnt4 + r * NB;
    int* bptr = bptr4 + r * (NB + 1);
    int* bcur = bcur4 + r * NB;
    const int tid = threadIdx.x;
    const int v = (tid < NB) ? cnt[tid] : 0;
    sa[tid] = v;
    int* cur = sa;
    int* nxt = sb;
    for (int d = 1; d < 512; d <<= 1) {
        __syncthreads();
        int t = cur[tid];
        if (tid >= d) t += cur[tid - d];
        nxt[tid] = t;
        int* tmp = cur; cur = nxt; nxt = tmp;
    }
    __syncthreads();
    const int excl = cur[tid] - v;
    if (tid <= NB) bptr[tid] = excl;
    if (tid < NB) bcur[tid] = excl;
}

// ---------------- partition: LDS counting-sort chunks into bucket runs -------
__global__ __launch_bounds__(256) void partition_kernel(const int* __restrict__ rows,
                                                        const int* __restrict__ cols,
                                                        const float* __restrict__ vals,
                                                        int* __restrict__ bcur,
                                                        int2* __restrict__ cv) {
    __shared__ int lh[NB], lptr[NB], lcur[NB], lbase[NB];
    __shared__ int sa[256], sb[256];
    __shared__ int2 st[CHUNK];
    const int tid = threadIdx.x;
    for (int i = tid; i < NB; i += 256) lh[i] = 0;
    __syncthreads();
    const int e0 = blockIdx.x * CHUNK;
    const int e1 = min(e0 + CHUNK, N_EDGES);
    const int cnt = e1 - e0;
    for (int i = e0 + tid; i < e1; i += 256) atomicAdd(&lh[rows[i] >> 7], 1);
    __syncthreads();
    const int p0 = (2 * tid < NB) ? lh[2 * tid] : 0;
    const int p1 = (2 * tid + 1 < NB) ? lh[2 * tid + 1] : 0;
    sa[tid] = p0 + p1;
    int* cur = sa;
    int* nxt = sb;
    for (int d = 1; d < 256; d <<= 1) {
        __syncthreads();
        int t = cur[tid];
        if (tid >= d) t += cur[tid - d];
        nxt[tid] = t;
        int* tmp = cur; cur = nxt; nxt = tmp;
    }
    __syncthreads();
    const int pe = cur[tid] - (p0 + p1);
    if (2 * tid < NB)     { lptr[2 * tid] = pe;           lcur[2 * tid] = pe; }
    if (2 * tid + 1 < NB) { lptr[2 * tid + 1] = pe + p0;  lcur[2 * tid + 1] = pe + p0; }
    __syncthreads();
    for (int i = e0 + tid; i < e1; i += 256) {
        const int row = rows[i];
        const int b = row >> 7;
        const int pos = atomicAdd(&lcur[b], 1);
        st[pos] = make_int2((int)(((u32)row << 16) | (u32)cols[i]), __float_as_int(vals[i]));
    }
    __syncthreads();
    for (int b = tid; b < NB; b += 256) {
        const int c = lh[b];
        int gb = 0;
        if (c) gb = atomicAdd(&bcur[b], c);
        lbase[b] = gb - lptr[b];
    }
    __syncthreads();
    for (int i = tid; i < cnt; i += 256) {
        const int2 e = st[i];
        const int b = (int)((u32)e.x >> 23);
        cv[lbase[b] + i] = e;
    }
}

// ------- per-bucket CSR: 128-bin counting sort with per-row PAD-to-8 ---------
// cv4 entry: {bf16(val):hi16 | col:lo16}. Pad entries are 0 (val=0,col=0).
// Bucket b's padded run lives at fixed base bptr[b] + b*BSLACK.
// row_se[row] = {start, start + padded_count} in cv4 index space.
__global__ __launch_bounds__(256) void bucket_csr(const int* __restrict__ bptr,
                                                  const int2* __restrict__ cv,
                                                  u32* __restrict__ cv4,
                                                  int2* __restrict__ row_se) {
    __shared__ int lh[128], lpexcl[128], lcur[128];
    __shared__ u32 st[STCAP];
    __shared__ int s_psize;
    const int b = blockIdx.x;
    const int s = bptr[b], e1 = bptr[b + 1];
    const int tid = threadIdx.x;
    if (tid < 128) lh[tid] = 0;
    __syncthreads();
    for (int i = s + tid; i < e1; i += 256)
        atomicAdd(&lh[((u32)cv[i].x >> 16) & 127u], 1);
    __syncthreads();
    if (tid < 64) {  // wave 0: scan padded counts (2 bins/lane)
        const int c0 = lh[2 * tid], c1 = lh[2 * tid + 1];
        const int p0 = (c0 + 7) & ~7, p1 = (c1 + 7) & ~7;
        int ssum = p0 + p1;
#pragma unroll
        for (int d = 1; d < 64; d <<= 1) {
            const int t = __shfl_up(ssum, d, 64);
            if (tid >= d) ssum += t;
        }
        const int pe = ssum - (p0 + p1);
        lpexcl[2 * tid] = pe;          lcur[2 * tid] = pe;
        lpexcl[2 * tid + 1] = pe + p0; lcur[2 * tid + 1] = pe + p0;
        if (tid == 63) s_psize = ssum;
    }
    __syncthreads();
    const int psize = s_psize;
    for (int i = tid; i < psize; i += 256) st[i] = 0u;  // pre-fill pads with 0
    __syncthreads();
    for (int i = s + tid; i < e1; i += 256) {
        const int2 E = cv[i];
        const int lr = (int)(((u32)E.x >> 16) & 127u);
        const int pos = atomicAdd(&lcur[lr], 1);
        if (pos < STCAP)
            st[pos] = ((u32)f2bf(__int_as_float(E.y)) << 16) | ((u32)E.x & 0xFFFFu);
    }
    __syncthreads();
    const int pbase = s + b * BSLACK;
    for (int i = tid; i < psize; i += 256) cv4[pbase + i] = st[i];
    if (tid < 128) {
        const int row = (b << 7) + tid;
        if (row < N_NODES) {
            const int start = pbase + lpexcl[tid];
            const int pc = (lh[tid] + 7) & ~7;
            row_se[row] = make_int2(start, start + pc);
        }
    }
}

// ------------- sliced SpMM pass 1: y = bf16( filt * (A @ h) ) ----------------
// slice = blockIdx&3 (XCD k -> slice k&3; 3.2 MB operand slice L2-resident).
// Wave per (row, slice). Lane: es=lane>>3 (edge slot), cp=lane&7 (col pair-pair).
// 8 lanes x uint2 = one full 64B line per edge; 8 edges per gather instruction.
__global__ __launch_bounds__(256) void spmm1(const int2* __restrict__ row_se,
                                             const u32* __restrict__ cvp,
                                             const u32* __restrict__ hsl,
                                             const float* __restrict__ filt_r,
                                             u32* __restrict__ ysl) {
    const int slice = blockIdx.x & 3;
    const int w = threadIdx.x >> 6;
    const int lane = threadIdx.x & 63;
    const int row = __builtin_amdgcn_readfirstlane((blockIdx.x >> 2) * 4 + w);
    const int es = lane >> 3;
    const int cp = lane & 7;
    const u32* hs = hsl + (size_t)slice * N_NODES * 16;
    const int2 se = row_se[row];
    int e = se.x;
    const int end = se.y;
    float a0 = 0.f, a1 = 0.f, a2 = 0.f, a3 = 0.f;
    float b0 = 0.f, b1 = 0.f, b2 = 0.f, b3 = 0.f;
    for (; e + 16 <= end; e += 16) {
        const uint2 c = *(const uint2*)(cvp + e + 2 * es);  // edges e+2es, e+2es+1
        const uint2 gA = *(const uint2*)(hs + (c.x & 0xFFFFu) * 16 + 2 * cp);
        const uint2 gB = *(const uint2*)(hs + (c.y & 0xFFFFu) * 16 + 2 * cp);
        const float vA = __uint_as_float(c.x & 0xFFFF0000u);
        const float vB = __uint_as_float(c.y & 0xFFFF0000u);
        a0 += vA * bf_lo(gA.x); a1 += vA * bf_hi(gA.x);
        a2 += vA * bf_lo(gA.y); a3 += vA * bf_hi(gA.y);
        b0 += vB * bf_lo(gB.x); b1 += vB * bf_hi(gB.x);
        b2 += vB * bf_lo(gB.y); b3 += vB * bf_hi(gB.y);
    }
    if (e < end) {  // exactly 8 padded edges remain; groups es>=4 masked to pad
        const uint2 c = *(const uint2*)(cvp + e + 2 * es);
        const u32 ux = (es < 4) ? c.x : 0u;
        const u32 uy = (es < 4) ? c.y : 0u;
        const uint2 gA = *(const uint2*)(hs + (ux & 0xFFFFu) * 16 + 2 * cp);
        const uint2 gB = *(const uint2*)(hs + (uy & 0xFFFFu) * 16 + 2 * cp);
        const float vA = __uint_as_float(ux & 0xFFFF0000u);
        const float vB = __uint_as_float(uy & 0xFFFF0000u);
        a0 += vA * bf_lo(gA.x); a1 += vA * bf_hi(gA.x);
        a2 += vA * bf_lo(gA.y); a3 += vA * bf_hi(gA.y);
        b0 += vB * bf_lo(gB.x); b1 += vB * bf_hi(gB.x);
        b2 += vB * bf_lo(gB.y); b3 += vB * bf_hi(gB.y);
    }
    a0 += b0; a1 += b1; a2 += b2; a3 += b3;
    a0 += __shfl_xor(a0, 8, 64);  a1 += __shfl_xor(a1, 8, 64);
    a2 += __shfl_xor(a2, 8, 64);  a3 += __shfl_xor(a3, 8, 64);
    a0 += __shfl_xor(a0, 16, 64); a1 += __shfl_xor(a1, 16, 64);
    a2 += __shfl_xor(a2, 16, 64); a3 += __shfl_xor(a3, 16, 64);
    a0 += __shfl_xor(a0, 32, 64); a1 += __shfl_xor(a1, 32, 64);
    a2 += __shfl_xor(a2, 32, 64); a3 += __shfl_xor(a3, 32, 64);
    const float f = filt_r[row];
    if (lane < 8) {
        uint2 o;
        o.x = (u32)f2bf(f * a0) | ((u32)f2bf(f * a1) << 16);
        o.y = (u32)f2bf(f * a2) | ((u32)f2bf(f * a3) << 16);
        *(uint2*)(ysl + (size_t)slice * N_NODES * 16 + (size_t)row * 16 + 2 * lane) = o;
    }
}

// ------------- sliced SpMM pass 2: out (+)= A @ y  (fp32 out) ----------------
template <bool FIRST>
__global__ __launch_bounds__(256) void spmm2(const int2* __restrict__ row_se,
                                             const u32* __restrict__ cvp,
                                             const u32* __restrict__ ysl,
                                             const float* __restrict__ bias,
                                             float* __restrict__ out) {
    const int slice = blockIdx.x & 3;
    const int w = threadIdx.x >> 6;
    const int lane = threadIdx.x & 63;
    const int row = __builtin_amdgcn_readfirstlane((blockIdx.x >> 2) * 4 + w);
    const int es = lane >> 3;
    const int cp = lane & 7;
    const u32* ys = ysl + (size_t)slice * N_NODES * 16;
    const int2 se = row_se[row];
    int e = se.x;
    const int end = se.y;
    float a0 = 0.f, a1 = 0.f, a2 = 0.f, a3 = 0.f;
    float b0 = 0.f, b1 = 0.f, b2 = 0.f, b3 = 0.f;
    for (; e + 16 <= end; e += 16) {
        const uint2 c = *(const uint2*)(cvp + e + 2 * es);
        const uint2 gA = *(const uint2*)(ys + (c.x & 0xFFFFu) * 16 + 2 * cp);
        const uint2 gB = *(const uint2*)(ys + (c.y & 0xFFFFu) * 16 + 2 * cp);
        const float vA = __uint_as_float(c.x & 0xFFFF0000u);
        const float vB = __uint_as_float(c.y & 0xFFFF0000u);
        a0 += vA * bf_lo(gA.x); a1 += vA * bf_hi(gA.x);
        a2 += vA * bf_lo(gA.y); a3 += vA * bf_hi(gA.y);
        b0 += vB * bf_lo(gB.x); b1 += vB * bf_hi(gB.x);
        b2 += vB * bf_lo(gB.y); b3 += vB * bf_hi(gB.y);
    }
    if (e < end) {
        const uint2 c = *(const uint2*)(cvp + e + 2 * es);
        const u32 ux = (es < 4) ? c.x : 0u;
        const u32 uy = (es < 4) ? c.y : 0u;
        const uint2 gA = *(const uint2*)(ys + (ux & 0xFFFFu) * 16 + 2 * cp);
        const uint2 gB = *(const uint2*)(ys + (uy & 0xFFFFu) * 16 + 2 * cp);
        const float vA = __uint_as_float(ux & 0xFFFF0000u);
        const float vB = __uint_as_float(uy & 0xFFFF0000u);
        a0 += vA * bf_lo(gA.x); a1 += vA * bf_hi(gA.x);
        a2 += vA * bf_lo(gA.y); a3 += vA * bf_hi(gA.y);
        b0 += vB * bf_lo(gB.x); b1 += vB * bf_hi(gB.x);
        b2 += vB * bf_lo(gB.y); b3 += vB * bf_hi(gB.y);
    }
    a0 += b0; a1 += b1; a2 += b2; a3 += b3;
    a0 += __shfl_xor(a0, 8, 64);  a1 += __shfl_xor(a1, 8, 64);
    a2 += __shfl_xor(a2, 8, 64);  a3 += __shfl_xor(a3, 8, 64);
    a0 += __shfl_xor(a0, 16, 64); a1 += __shfl_xor(a1, 16, 64);
    a2 += __shfl_xor(a2, 16, 64); a3 += __shfl_xor(a3, 16, 64);
    a0 += __shfl_xor(a0, 32, 64); a1 += __shfl_xor(a1, 32, 64);
    a2 += __shfl_xor(a2, 32, 64); a3 += __shfl_xor(a3, 32, 64);
    if (lane < 8) {
        float* op = out + (size_t)row * D + slice * 32 + 4 * lane;
        if (FIRST) {
            const float4 bb = *(const float4*)(bias + slice * 32 + 4 * lane);
            *(float4*)op = make_float4(a0 + bb.x, a1 + bb.y, a2 + bb.z, a3 + bb.w);
        } else {
            const float4 cc = *(const float4*)op;
            *(float4*)op = make_float4(cc.x + a0, cc.y + a1, cc.z + a2, cc.w + a3);
        }
    }
}

extern "C" void kernel_launch(void* const* d_in, const int* in_sizes, int n_in,
                              void* d_out, int out_size, void* d_ws, size_t ws_size,
                              hipStream_t stream) {
    const float* x    = (const float*)d_in[0];  // [N,128]
    const float* vals = (const float*)d_in[1];  // [R,E]
    const float* W    = (const float*)d_in[2];  // [128,128]
    const float* filt = (const float*)d_in[3];  // [R*N,1]
    const float* bias = (const float*)d_in[4];  // [128]
    const int*   rows = (const int*)d_in[5];    // [R,E]
    const int*   cols = (const int*)d_in[6];    // [R,E]
    float* out = (float*)d_out;                 // [N,128]

    char* ws = (char*)d_ws;
    u16*  h       = (u16*)(ws);                    // 12,800,000 B bf16 sliced [4][N][32]
    u32*  y2      = (u32*)(ws + 12800000);         // 12,800,000 B bf16 sliced [4][N][32]
    int2* cv8     = (int2*)(ws + 25600000);        // 12,800,000 B
    u32*  cv4     = (u32*)(ws + 38400000);         //  8,400,000 B (padded edges + slack)
    int2* row_se  = (int2*)(ws + 46800000);        //    400,000 B
    int*  cnt4    = (int*)(ws + 47200000);         // 4*NB
    int*  bptr4   = (int*)(ws + 47208192);         // 4*(NB+1)
    int*  bcur4   = (int*)(ws + 47216384);         // 4*NB

    gemm_xw<<<N_NODES / 4, 128, 0, stream>>>(x, W, h);

    hipMemsetAsync(cnt4, 0, 4 * NB * sizeof(int), stream);
    bucket_hist_all<<<dim3(NPBLK, R_WAV), 256, 0, stream>>>(rows, cnt4);
    scan_buckets_all<<<R_WAV, 512, 0, stream>>>(cnt4, bptr4, bcur4);

    for (int r = 0; r < R_WAV; ++r) {
        const int*   rows_r = rows + (size_t)r * N_EDGES;
        const int*   cols_r = cols + (size_t)r * N_EDGES;
        const float* vals_r = vals + (size_t)r * N_EDGES;
        const float* filt_r = filt + (size_t)r * N_NODES;

        partition_kernel<<<NPBLK, 256, 0, stream>>>(rows_r, cols_r, vals_r,
                                                    bcur4 + r * NB, cv8);
        bucket_csr<<<NB, 256, 0, stream>>>(bptr4 + r * (NB + 1), cv8, cv4, row_se);
        // grid: 12500 row-groups x 4 slices; slice = blockIdx & 3 -> XCD-pinned
        spmm1<<<N_NODES, 256, 0, stream>>>(row_se, cv4, (const u32*)h, filt_r, y2);
        if (r == 0)
            spmm2<true><<<N_NODES, 256, 0, stream>>>(row_se, cv4, y2, bias, out);
        else
            spmm2<false><<<N_NODES, 256, 0, stream>>>(row_se, cv4, y2, bias, out);
    }
}

// Round 7
// 793.911 us; speedup vs baseline: 1.1749x; 1.1749x over previous
//
#include <hip/hip_runtime.h>

#define N_NODES 50000
#define N_EDGES 1600000
#define R_WAV 4
#define D 128
#define NB 391                 // ceil(50000/128) buckets of 128 rows
#define CHUNK 4096             // edges per hist/partition block
#define NPBLK ((N_EDGES + CHUNK - 1) / CHUNK)   // 391
#define MAXB 4800              // bucket capacity for LDS sort (mean 4092, sigma 64)
#define RP_STRIDE 50016        // row_ptr slot stride in ints (N+1 padded)

typedef unsigned int u32;
typedef unsigned short u16;

// fp32 -> bf16 bits, round-to-nearest-even
static __device__ inline u16 f2bf(float f) {
    u32 u = __float_as_uint(f);
    u = (u + 0x7FFFu + ((u >> 16) & 1u)) >> 16;
    return (u16)u;
}
static __device__ inline float bf_lo(u32 u) { return __uint_as_float(u << 16); }
static __device__ inline float bf_hi(u32 u) { return __uint_as_float(u & 0xFFFF0000u); }

// ---------------- GEMM: h = x @ W, bf16 row-major [N][128] -------------------
__global__ __launch_bounds__(128) void gemm_xw(const float* __restrict__ x,
                                               const float* __restrict__ W,
                                               u16* __restrict__ h) {
    __shared__ float xs[4 * 128];
    const int j = threadIdx.x;
    const int row0 = blockIdx.x * 4;
    for (int t = j; t < 512; t += 128) xs[t] = x[(size_t)row0 * D + t];
    __syncthreads();
    float a0 = 0.f, a1 = 0.f, a2 = 0.f, a3 = 0.f;
#pragma unroll 8
    for (int k = 0; k < 128; ++k) {
        const float w = W[k * D + j];
        a0 += xs[k] * w;
        a1 += xs[128 + k] * w;
        a2 += xs[256 + k] * w;
        a3 += xs[384 + k] * w;
    }
    h[(size_t)(row0 + 0) * D + j] = f2bf(a0);
    h[(size_t)(row0 + 1) * D + j] = f2bf(a1);
    h[(size_t)(row0 + 2) * D + j] = f2bf(a2);
    h[(size_t)(row0 + 3) * D + j] = f2bf(a3);
}

// ------------- batched bucket histogram: grid (NPBLK, R_WAV) -----------------
__global__ __launch_bounds__(256) void bucket_hist_all(const int* __restrict__ rows_all,
                                                       int* __restrict__ cnt4) {
    __shared__ int lh[NB];
    const int r = blockIdx.y;
    const int* rows = rows_all + (size_t)r * N_EDGES;
    int* cnt = cnt4 + r * NB;
    const int tid = threadIdx.x;
    for (int i = tid; i < NB; i += 256) lh[i] = 0;
    __syncthreads();
    const int e0 = blockIdx.x * CHUNK;
    const int e1 = min(e0 + CHUNK, N_EDGES);
    for (int i = e0 + tid; i < e1; i += 256) atomicAdd(&lh[rows[i] >> 7], 1);
    __syncthreads();
    for (int i = tid; i < NB; i += 256) {
        const int c = lh[i];
        if (c) atomicAdd(&cnt[i], c);
    }
}

// ------------- batched scan of bucket counts: grid R_WAV ---------------------
__global__ __launch_bounds__(512) void scan_buckets_all(const int* __restrict__ cnt4,
                                                        int* __restrict__ bptr4,
                                                        int* __restrict__ bcur4) {
    __shared__ int sa[512], sb[512];
    const int r = blockIdx.x;
    const int* cnt = cnt4 + r * NB;
    int* bptr = bptr4 + r * (NB + 1);
    int* bcur = bcur4 + r * NB;
    const int tid = threadIdx.x;
    const int v = (tid < NB) ? cnt[tid] : 0;
    sa[tid] = v;
    int* cur = sa;
    int* nxt = sb;
    for (int d = 1; d < 512; d <<= 1) {
        __syncthreads();
        int t = cur[tid];
        if (tid >= d) t += cur[tid - d];
        nxt[tid] = t;
        int* tmp = cur; cur = nxt; nxt = tmp;
    }
    __syncthreads();
    const int excl = cur[tid] - v;
    if (tid <= NB) bptr[tid] = excl;
    if (tid < NB) bcur[tid] = excl;
}

// ------ batched partition: grid (NPBLK, 2) — LDS counting-sort into runs -----
__global__ __launch_bounds__(256) void partition_all(const int* __restrict__ rows_all,
                                                     const int* __restrict__ cols_all,
                                                     const float* __restrict__ vals_all,
                                                     int rbase,
                                                     int* __restrict__ bcur4,
                                                     int2* __restrict__ cv8base) {
    __shared__ int lh[NB], lptr[NB], lcur[NB], lbase[NB];
    __shared__ int sa[256], sb[256];
    __shared__ int2 st[CHUNK];
    const int slot = blockIdx.y;
    const int r = rbase + slot;
    const int* rows = rows_all + (size_t)r * N_EDGES;
    const int* cols = cols_all + (size_t)r * N_EDGES;
    const float* vals = vals_all + (size_t)r * N_EDGES;
    int* bcur = bcur4 + r * NB;
    int2* cv = cv8base + (size_t)slot * N_EDGES;
    const int tid = threadIdx.x;
    for (int i = tid; i < NB; i += 256) lh[i] = 0;
    __syncthreads();
    const int e0 = blockIdx.x * CHUNK;
    const int e1 = min(e0 + CHUNK, N_EDGES);
    const int cnt = e1 - e0;
    for (int i = e0 + tid; i < e1; i += 256) atomicAdd(&lh[rows[i] >> 7], 1);
    __syncthreads();
    const int p0 = (2 * tid < NB) ? lh[2 * tid] : 0;
    const int p1 = (2 * tid + 1 < NB) ? lh[2 * tid + 1] : 0;
    sa[tid] = p0 + p1;
    int* cur = sa;
    int* nxt = sb;
    for (int d = 1; d < 256; d <<= 1) {
        __syncthreads();
        int t = cur[tid];
        if (tid >= d) t += cur[tid - d];
        nxt[tid] = t;
        int* tmp = cur; cur = nxt; nxt = tmp;
    }
    __syncthreads();
    const int pe = cur[tid] - (p0 + p1);
    if (2 * tid < NB)     { lptr[2 * tid] = pe;           lcur[2 * tid] = pe; }
    if (2 * tid + 1 < NB) { lptr[2 * tid + 1] = pe + p0;  lcur[2 * tid + 1] = pe + p0; }
    __syncthreads();
    for (int i = e0 + tid; i < e1; i += 256) {
        const int row = rows[i];
        const int b = row >> 7;
        const int pos = atomicAdd(&lcur[b], 1);
        st[pos] = make_int2((int)(((u32)row << 16) | (u32)cols[i]), __float_as_int(vals[i]));
    }
    __syncthreads();
    for (int b = tid; b < NB; b += 256) {
        const int c = lh[b];
        int gb = 0;
        if (c) gb = atomicAdd(&bcur[b], c);
        lbase[b] = gb - lptr[b];
    }
    __syncthreads();
    for (int i = tid; i < cnt; i += 256) {
        const int2 e = st[i];
        const int b = (int)((u32)e.x >> 23);
        cv[lbase[b] + i] = e;
    }
}

// ------ batched per-bucket CSR: grid (NB, 2) — sort + emit 4B edges ----------
// cv4 entry: {bf16(val) : hi16, col : lo16}
__global__ __launch_bounds__(256) void bucket_csr_all(const int* __restrict__ bptr4,
                                                      int rbase,
                                                      const int2* __restrict__ cv8base,
                                                      u32* __restrict__ cv4base,
                                                      int* __restrict__ rp_base) {
    __shared__ int lh[128], lexcl[128], lcur[128];
    __shared__ u32 st[MAXB];
    const int slot = blockIdx.y;
    const int r = rbase + slot;
    const int* bptr = bptr4 + r * (NB + 1);
    const int2* cv = cv8base + (size_t)slot * N_EDGES;
    u32* cv4 = cv4base + (size_t)slot * N_EDGES;
    int* row_ptr = rp_base + slot * RP_STRIDE;
    const int b = blockIdx.x;
    const int s = bptr[b], e1 = bptr[b + 1];
    const int cnt = e1 - s;
    const int tid = threadIdx.x;
    if (tid < 128) lh[tid] = 0;
    __syncthreads();
    for (int i = s + tid; i < e1; i += 256)
        atomicAdd(&lh[((u32)cv[i].x >> 16) & 127u], 1);
    __syncthreads();
    if (tid < 64) {
        const int p0 = lh[2 * tid], p1 = lh[2 * tid + 1];
        int ssum = p0 + p1;
#pragma unroll
        for (int d = 1; d < 64; d <<= 1) {
            const int t = __shfl_up(ssum, d, 64);
            if (tid >= d) ssum += t;
        }
        const int pe = ssum - (p0 + p1);
        lexcl[2 * tid] = pe;          lcur[2 * tid] = pe;
        lexcl[2 * tid + 1] = pe + p0; lcur[2 * tid + 1] = pe + p0;
    }
    __syncthreads();
    for (int i = s + tid; i < e1; i += 256) {
        const int2 E = cv[i];
        const int lr = (int)(((u32)E.x >> 16) & 127u);
        const int pos = atomicAdd(&lcur[lr], 1);
        if (pos < MAXB)
            st[pos] = ((u32)f2bf(__int_as_float(E.y)) << 16) | ((u32)E.x & 0xFFFFu);
    }
    __syncthreads();
    const int wb = (cnt < MAXB) ? cnt : MAXB;
    for (int i = tid; i < wb; i += 256) cv4[s + i] = st[i];
    if (tid < 128) {
        const int row = (b << 7) + tid;
        if (row < N_NODES) row_ptr[row] = s + lexcl[tid];
    }
    if (b == 0 && tid == 0) row_ptr[N_NODES] = N_EDGES;
}

// --------- shared accumulation loop: wave-per-row, 256 B/edge gathers --------
// 2 edges per gather instruction (lanes 0-31 edge k, lanes 32-63 edge k+1);
// lane owns cols 4l..4l+3 via uint2.
static __device__ inline void spmm_accum(const int* __restrict__ rp,
                                         const u32* __restrict__ cvp,
                                         const u32* __restrict__ src,
                                         int row, int half, int l,
                                         float& a0, float& a1, float& a2, float& a3,
                                         float& b0, float& b1, float& b2, float& b3) {
    int e = rp[row];
    const int end = rp[row + 1];
    for (; e + 8 <= end; e += 8) {
        const u32 c0 = cvp[e], c1 = cvp[e + 1], c2 = cvp[e + 2], c3 = cvp[e + 3];
        const u32 c4 = cvp[e + 4], c5 = cvp[e + 5], c6 = cvp[e + 6], c7 = cvp[e + 7];
        const u32 uA = half ? c1 : c0;
        const u32 uB = half ? c3 : c2;
        const u32 uC = half ? c5 : c4;
        const u32 uD = half ? c7 : c6;
        const uint2 gA = *(const uint2*)(src + (uA & 0xFFFFu) * 64 + 2 * l);
        const uint2 gB = *(const uint2*)(src + (uB & 0xFFFFu) * 64 + 2 * l);
        const uint2 gC = *(const uint2*)(src + (uC & 0xFFFFu) * 64 + 2 * l);
        const uint2 gD = *(const uint2*)(src + (uD & 0xFFFFu) * 64 + 2 * l);
        const float vA = __uint_as_float(uA & 0xFFFF0000u);
        const float vB = __uint_as_float(uB & 0xFFFF0000u);
        const float vC = __uint_as_float(uC & 0xFFFF0000u);
        const float vD = __uint_as_float(uD & 0xFFFF0000u);
        a0 += vA * bf_lo(gA.x); a1 += vA * bf_hi(gA.x);
        a2 += vA * bf_lo(gA.y); a3 += vA * bf_hi(gA.y);
        b0 += vB * bf_lo(gB.x); b1 += vB * bf_hi(gB.x);
        b2 += vB * bf_lo(gB.y); b3 += vB * bf_hi(gB.y);
        a0 += vC * bf_lo(gC.x); a1 += vC * bf_hi(gC.x);
        a2 += vC * bf_lo(gC.y); a3 += vC * bf_hi(gC.y);
        b0 += vD * bf_lo(gD.x); b1 += vD * bf_hi(gD.x);
        b2 += vD * bf_lo(gD.y); b3 += vD * bf_hi(gD.y);
    }
    for (; e < end; e += 2) {
        const u32 c0 = cvp[e];
        const u32 c1 = (e + 1 < end) ? cvp[e + 1] : 0u;
        const u32 uA = half ? c1 : c0;
        const uint2 gA = *(const uint2*)(src + (uA & 0xFFFFu) * 64 + 2 * l);
        const float vA = __uint_as_float(uA & 0xFFFF0000u);
        a0 += vA * bf_lo(gA.x); a1 += vA * bf_hi(gA.x);
        a2 += vA * bf_lo(gA.y); a3 += vA * bf_hi(gA.y);
    }
}

// ---------------- SpMM pass 1: y = bf16( filt * (A @ h) ) --------------------
__global__ __launch_bounds__(256) void spmm1(const int* __restrict__ row_ptr,
                                             const u32* __restrict__ cvp,
                                             const u32* __restrict__ h2,
                                             const float* __restrict__ filt_r,
                                             u32* __restrict__ y2) {
    const int row = __builtin_amdgcn_readfirstlane(blockIdx.x * 4 + (threadIdx.x >> 6));
    const int lane = threadIdx.x & 63;
    const int half = lane >> 5;
    const int l = lane & 31;
    float a0 = 0.f, a1 = 0.f, a2 = 0.f, a3 = 0.f;
    float b0 = 0.f, b1 = 0.f, b2 = 0.f, b3 = 0.f;
    spmm_accum(row_ptr, cvp, h2, row, half, l, a0, a1, a2, a3, b0, b1, b2, b3);
    a0 += b0; a1 += b1; a2 += b2; a3 += b3;
    a0 += __shfl_xor(a0, 32, 64);
    a1 += __shfl_xor(a1, 32, 64);
    a2 += __shfl_xor(a2, 32, 64);
    a3 += __shfl_xor(a3, 32, 64);
    const float f = filt_r[row];
    if (half == 0) {
        uint2 o;
        o.x = (u32)f2bf(f * a0) | ((u32)f2bf(f * a1) << 16);
        o.y = (u32)f2bf(f * a2) | ((u32)f2bf(f * a3) << 16);
        *(uint2*)(y2 + (size_t)row * 64 + 2 * l) = o;
    }
}

// ------------ fused SpMM pass 2 for an r-pair: out (+)= A_a@y_a + A_b@y_b ----
template <bool FIRST>
__global__ __launch_bounds__(256) void spmm2_pair(const int* __restrict__ rpa,
                                                  const int* __restrict__ rpb,
                                                  const u32* __restrict__ cva,
                                                  const u32* __restrict__ cvb,
                                                  const u32* __restrict__ ya,
                                                  const u32* __restrict__ yb,
                                                  const float* __restrict__ bias,
                                                  float* __restrict__ out) {
    const int row = __builtin_amdgcn_readfirstlane(blockIdx.x * 4 + (threadIdx.x >> 6));
    const int lane = threadIdx.x & 63;
    const int half = lane >> 5;
    const int l = lane & 31;
    float a0 = 0.f, a1 = 0.f, a2 = 0.f, a3 = 0.f;
    float b0 = 0.f, b1 = 0.f, b2 = 0.f, b3 = 0.f;
    spmm_accum(rpa, cva, ya, row, half, l, a0, a1, a2, a3, b0, b1, b2, b3);
    spmm_accum(rpb, cvb, yb, row, half, l, a0, a1, a2, a3, b0, b1, b2, b3);
    a0 += b0; a1 += b1; a2 += b2; a3 += b3;
    a0 += __shfl_xor(a0, 32, 64);
    a1 += __shfl_xor(a1, 32, 64);
    a2 += __shfl_xor(a2, 32, 64);
    a3 += __shfl_xor(a3, 32, 64);
    if (half == 0) {
        float* op = out + (size_t)row * D + 4 * l;
        if (FIRST) {
            const float4 bb = *(const float4*)(bias + 4 * l);
            *(float4*)op = make_float4(a0 + bb.x, a1 + bb.y, a2 + bb.z, a3 + bb.w);
        } else {
            const float4 cc = *(const float4*)op;
            *(float4*)op = make_float4(cc.x + a0, cc.y + a1, cc.z + a2, cc.w + a3);
        }
    }
}

extern "C" void kernel_launch(void* const* d_in, const int* in_sizes, int n_in,
                              void* d_out, int out_size, void* d_ws, size_t ws_size,
                              hipStream_t stream) {
    const float* x    = (const float*)d_in[0];  // [N,128]
    const float* vals = (const float*)d_in[1];  // [R,E]
    const float* W    = (const float*)d_in[2];  // [128,128]
    const float* filt = (const float*)d_in[3];  // [R*N,1]
    const float* bias = (const float*)d_in[4];  // [128]
    const int*   rows = (const int*)d_in[5];    // [R,E]
    const int*   cols = (const int*)d_in[6];    // [R,E]
    float* out = (float*)d_out;                 // [N,128]

    // ws layout (51.6 MB total; y2 slots alias the dead cv8 slots):
    //   h       [0,            12,800,000)   bf16 [N][128]
    //   cv4 x2  [12,800,000,   25,600,000)   packed 4B edges, 2 slots
    //   row_ptr [25,600,000,   26,000,128)   2 slots x RP_STRIDE ints
    //   cnt4/bptr4/bcur4 small arrays
    //   U       [26,018,912,   51,618,912)   union: cv8 x2 (int2) / y2 x2 (u32)
    char* ws = (char*)d_ws;
    u16*  h       = (u16*)(ws);
    u32*  cv4     = (u32*)(ws + 12800000);
    int*  row_ptr = (int*)(ws + 25600000);
    int*  cnt4    = (int*)(ws + 26000128);
    int*  bptr4   = (int*)(ws + 26006384);
    int*  bcur4   = (int*)(ws + 26012656);
    int2* cv8     = (int2*)(ws + 26018912);
    u32*  y2      = (u32*)(ws + 26018912);

    gemm_xw<<<N_NODES / 4, 128, 0, stream>>>(x, W, h);

    hipMemsetAsync(cnt4, 0, 4 * NB * sizeof(int), stream);
    bucket_hist_all<<<dim3(NPBLK, R_WAV), 256, 0, stream>>>(rows, cnt4);
    scan_buckets_all<<<R_WAV, 512, 0, stream>>>(cnt4, bptr4, bcur4);

    for (int p = 0; p < 2; ++p) {
        const int rbase = 2 * p;
        // build both CSRs of the pair (cv8 slots live here)
        partition_all<<<dim3(NPBLK, 2), 256, 0, stream>>>(rows, cols, vals, rbase,
                                                          bcur4, cv8);
        bucket_csr_all<<<dim3(NB, 2), 256, 0, stream>>>(bptr4, rbase, cv8, cv4, row_ptr);
        // y2 slots overwrite cv8 slots (already consumed)
        spmm1<<<N_NODES / 4, 256, 0, stream>>>(row_ptr, cv4, (const u32*)h,
                                               filt + (size_t)rbase * N_NODES,
                                               y2);
        spmm1<<<N_NODES / 4, 256, 0, stream>>>(row_ptr + RP_STRIDE, cv4 + N_EDGES,
                                               (const u32*)h,
                                               filt + (size_t)(rbase + 1) * N_NODES,
                                               y2 + 3200000);
        if (p == 0)
            spmm2_pair<true><<<N_NODES / 4, 256, 0, stream>>>(
                row_ptr, row_ptr + RP_STRIDE, cv4, cv4 + N_EDGES,
                y2, y2 + 3200000, bias, out);
        else
            spmm2_pair<false><<<N_NODES / 4, 256, 0, stream>>>(
                row_ptr, row_ptr + RP_STRIDE, cv4, cv4 + N_EDGES,
                y2, y2 + 3200000, bias, out);
    }
}